// Round 2
// baseline (25091.125 us; speedup 1.0000x reference)
//
#include <hip/hip_runtime.h>
#include <stdint.h>

#define DEVINL __device__ __forceinline__

constexpr int B_  = 32;
constexpr int S_  = 512;
constexpr int I_  = 768;
constexpr int H_  = 512;
constexpr int C_  = 10;
constexpr int R_  = 64;     // 2 dirs * B_
constexpr int G4H = 2048;   // 4*H_
constexpr int I2_ = 1536;   // 2*I_

using bf16x8 = __attribute__((ext_vector_type(8))) short;
using f32x4  = __attribute__((ext_vector_type(4))) float;
typedef unsigned short u16;
typedef unsigned int   u32;

// ---------------- workspace layout (bytes) ----------------
constexpr size_t OFF_TE   = 0;                                   // u16 [B_*S_][H_]  tanh(enc_proj)
constexpr size_t OFF_EMB  = OFF_TE   + (size_t)B_*S_*H_*2;       // u16 [B_*S_][I_]  embeds bf16
constexpr size_t OFF_WDEC = OFF_EMB  + (size_t)B_*S_*I_*2;       // u16 [H_][H_]
constexpr size_t OFF_WHH  = OFF_WDEC + (size_t)H_*H_*2;          // u16 [2][G4H][H_]
constexpr size_t OFF_WIL  = OFF_WHH  + (size_t)2*G4H*H_*2;       // u16 [2][G4H][I_] Wih cols 0..767
constexpr size_t OFF_WIR  = OFF_WIL  + (size_t)2*G4H*I_*2;       // u16 [2][G4H][I_] Wih cols 768..1535
constexpr size_t OFF_WENC = OFF_WIR  + (size_t)2*G4H*I_*2;       // u16 [H_][I_]
constexpr size_t OFF_H    = OFF_WENC + (size_t)H_*I_*2;          // u16 [R_][H_]   h state (bf16)
constexpr size_t OFF_C    = OFF_H    + (size_t)R_*H_*2;          // f32 [R_][H_]   c state
constexpr size_t OFF_TD   = OFF_C    + (size_t)R_*H_*4;          // f32 [R_][H_]   tanh(dec)
constexpr size_t OFF_HWH  = OFF_TD   + (size_t)R_*H_*4;          // f32 [R_][G4H]  h @ Whh^T
constexpr size_t OFF_XW   = OFF_HWH  + (size_t)R_*G4H*4;         // f32 [R_][G4H]  x_t @ WihR^T
constexpr size_t OFF_CTX  = OFF_XW   + (size_t)R_*G4H*4;         // f32 [R_][I_]   unnormalized ctx
constexpr size_t OFF_SUME = OFF_CTX  + (size_t)R_*I_*4;          // f32 [R_]
constexpr size_t OFF_M    = OFF_SUME + 256;                      // f32 [R_] running logsumexp shift
constexpr size_t WS_NEED  = OFF_M + 256;

// ---------------- helpers ----------------
DEVINL float asf(u32 u){ union{u32 i; float f;} x; x.i=u; return x.f; }
DEVINL u32   asu(float f){ union{u32 i; float f;} x; x.f=f; return x.i; }
DEVINL float bf2f(u16 h){ return asf((u32)h << 16); }
DEVINL u16   f2bf(float f){ u32 u = asu(f); return (u16)((u + 0x7fffu + ((u>>16)&1u)) >> 16); }
DEVINL float frcp(float x){
#if __has_builtin(__builtin_amdgcn_rcpf)
  return __builtin_amdgcn_rcpf(x);
#else
  return 1.0f/x;
#endif
}
DEVINL float sigm(float x){ return frcp(1.0f + __expf(-x)); }

// ---------------- one-time setup: zero state, convert weights ----------------
__global__ void k_setup(char* ws, const float* Wenc, const float* Wdec,
                        const float* Whh_f, const float* Whh_b,
                        const float* Wih_f, const float* Wih_b,
                        float* out){
  int tid = blockIdx.x*blockDim.x + threadIdx.x;
  int nth = gridDim.x*blockDim.x;
  for (int i = tid; i < B_*S_*C_; i += nth) out[i] = 0.f;
  u16* hB = (u16*)(ws+OFF_H);
  for (int i = tid; i < R_*H_; i += nth) hB[i] = 0;
  float* cS = (float*)(ws+OFF_C);
  for (int i = tid; i < R_*H_; i += nth) cS[i] = 0.f;
  float* mb = (float*)(ws+OFF_M);
  for (int i = tid; i < R_; i += nth) mb[i] = 0.f;
  u16* wd = (u16*)(ws+OFF_WDEC);
  for (int i = tid; i < H_*H_; i += nth) wd[i] = f2bf(Wdec[i]);
  u16* we = (u16*)(ws+OFF_WENC);
  for (int i = tid; i < H_*I_; i += nth) we[i] = f2bf(Wenc[i]);
  u16* wh = (u16*)(ws+OFF_WHH);
  for (int i = tid; i < G4H*H_; i += nth){
    wh[i] = f2bf(Whh_f[i]);
    wh[G4H*H_ + i] = f2bf(Whh_b[i]);
  }
  u16* wl = (u16*)(ws+OFF_WIL);
  u16* wr = (u16*)(ws+OFF_WIR);
  for (int i = tid; i < G4H*I_; i += nth){
    int n = i / I_, k = i - n*I_;
    wl[i]            = f2bf(Wih_f[n*I2_ + k]);
    wr[i]            = f2bf(Wih_f[n*I2_ + I_ + k]);
    wl[G4H*I_ + i]   = f2bf(Wih_b[n*I2_ + k]);
    wr[G4H*I_ + i]   = f2bf(Wih_b[n*I2_ + I_ + k]);
  }
}

// ---------------- one-time: embeds -> bf16 ----------------
__global__ void k_embconv(char* ws, const float* emb){
  u16* e = (u16*)(ws+OFF_EMB);
  int tid = blockIdx.x*blockDim.x + threadIdx.x;
  int nth = gridDim.x*blockDim.x;
  int n4 = (B_*S_*I_)/4;
  const float4* src = (const float4*)emb;
  ushort4* dst = (ushort4*)e;
  for (int i = tid; i < n4; i += nth){
    float4 x = src[i];
    ushort4 o;
    o.x = f2bf(x.x); o.y = f2bf(x.y); o.z = f2bf(x.z); o.w = f2bf(x.w);
    dst[i] = o;
  }
}

// ---------------- one-time: Te = tanh(embB @ WencB^T + benc) ----------------
__global__ __launch_bounds__(256) void k_enc(char* ws, const float* benc){
  const u16* A = (const u16*)(ws+OFF_EMB);
  const u16* W = (const u16*)(ws+OFF_WENC);
  u16* Te = (u16*)(ws+OFF_TE);
  int wg = blockIdx.x;               // 1024 m-tiles * 8 n-groups
  int mt = wg >> 3, ng = wg & 7;
  int wave = threadIdx.x >> 6, lane = threadIdx.x & 63;
  int m0 = mt*16, n0 = ng*64 + wave*16;
  int lr = lane & 15, lkb = (lane>>4)*8;
  const u16* ap = A + (size_t)(m0+lr)*I_ + lkb;
  const u16* bp = W + (size_t)(n0+lr)*I_ + lkb;
  f32x4 acc = {0.f,0.f,0.f,0.f};
  for (int k = 0; k < I_; k += 32){
    bf16x8 a = *(const bf16x8*)(ap + k);
    bf16x8 b = *(const bf16x8*)(bp + k);
    acc = __builtin_amdgcn_mfma_f32_16x16x32_bf16(a, b, acc, 0, 0, 0);
  }
  int row4 = (lane>>4)*4;
  #pragma unroll
  for (int q = 0; q < 4; q++){
    int rr = m0 + row4 + q, cc = n0 + lr;
    Te[(size_t)rr*H_ + cc] = f2bf(tanhf(acc[q] + benc[cc]));
  }
}

// ---------------- per-step K1: dec/Td, h@Whh^T, x_t@WihR^T, zero accums ----------------
__global__ __launch_bounds__(256) void k_step1(char* ws, const float* bdec, int t){
  int wg = blockIdx.x;
  if (wg >= 288){   // zero ctx & sumE
    int tid = (wg-288)*256 + threadIdx.x;
    float* ctx = (float*)(ws+OFF_CTX);
    for (int i = tid; i < R_*I_; i += 512) ctx[i] = 0.f;
    float* se = (float*)(ws+OFF_SUME);
    for (int i = tid; i < R_; i += 512) se[i] = 0.f;
    return;
  }
  int wave = threadIdx.x >> 6, lane = threadIdx.x & 63;
  int tile = wg*4 + wave;            // 0..1151
  int lr = lane & 15, lkb = (lane>>4)*8, row4 = (lane>>4)*4;
  const u16* hB = (const u16*)(ws+OFF_H);
  f32x4 acc = {0.f,0.f,0.f,0.f};
  if (tile < 128){                   // dec: M=64, N=512, K=512 (shared Wdec)
    int m0 = (tile>>5)*16, n0 = (tile&31)*16;
    const u16* W = (const u16*)(ws+OFF_WDEC);
    const u16* ap = hB + (size_t)(m0+lr)*H_ + lkb;
    const u16* bp = W + (size_t)(n0+lr)*H_ + lkb;
    for (int k = 0; k < H_; k += 32){
      bf16x8 a = *(const bf16x8*)(ap + k);
      bf16x8 b = *(const bf16x8*)(bp + k);
      acc = __builtin_amdgcn_mfma_f32_16x16x32_bf16(a, b, acc, 0, 0, 0);
    }
    float* Td = (float*)(ws+OFF_TD);
    #pragma unroll
    for (int q = 0; q < 4; q++){
      int rr = m0 + row4 + q, cc = n0 + lr;
      Td[rr*H_ + cc] = tanhf(acc[q] + bdec[cc]);
    }
  } else if (tile < 640){            // hWhh: per dir M=32, N=2048, K=512
    int t2 = tile - 128; int dir = t2 >> 8; int t3 = t2 & 255;
    int m0 = dir*32 + (t3>>7)*16;    // global row base
    int n0 = (t3 & 127)*16;
    const u16* W = (const u16*)(ws+OFF_WHH) + (size_t)dir*G4H*H_;
    const u16* ap = hB + (size_t)(m0+lr)*H_ + lkb;
    const u16* bp = W + (size_t)(n0+lr)*H_ + lkb;
    for (int k = 0; k < H_; k += 32){
      bf16x8 a = *(const bf16x8*)(ap + k);
      bf16x8 b = *(const bf16x8*)(bp + k);
      acc = __builtin_amdgcn_mfma_f32_16x16x32_bf16(a, b, acc, 0, 0, 0);
    }
    float* o = (float*)(ws+OFF_HWH);
    #pragma unroll
    for (int q = 0; q < 4; q++){
      int rr = m0 + row4 + q;
      o[(size_t)rr*G4H + n0 + lr] = acc[q];
    }
  } else {                           // xW: per dir M=32, N=2048, K=768
    int t2 = tile - 640; int dir = t2 >> 8; int t3 = t2 & 255;
    int bbase = (t3>>7)*16;
    int n0 = (t3 & 127)*16;
    int trow = dir ? (S_-1-t) : t;
    const u16* E = (const u16*)(ws+OFF_EMB);
    const u16* W = (const u16*)(ws+OFF_WIR) + (size_t)dir*G4H*I_;
    const u16* ap = E + ((size_t)(bbase+lr)*S_ + trow)*I_ + lkb;
    const u16* bp = W + (size_t)(n0+lr)*I_ + lkb;
    for (int k = 0; k < I_; k += 32){
      bf16x8 a = *(const bf16x8*)(ap + k);
      bf16x8 b = *(const bf16x8*)(bp + k);
      acc = __builtin_amdgcn_mfma_f32_16x16x32_bf16(a, b, acc, 0, 0, 0);
    }
    float* o = (float*)(ws+OFF_XW);
    #pragma unroll
    for (int q = 0; q < 4; q++){
      int bb = bbase + row4 + q;
      o[(size_t)(dir*32+bb)*G4H + n0 + lr] = acc[q];
    }
  }
}

// ---------------- per-step K2: scores via tanh-addition, exp, ctx partials ----------------
__global__ __launch_bounds__(512) void k_attn(char* ws, const float* v){
  int wg = blockIdx.x;                 // 256 = 8 pairs * 32 b
  int b = wg & 31, pair = wg >> 5;     // pair 0..7, chunk size 32
  int s0A = pair*32, s0B = S_ - pair*32 - 32;
  int tid = threadIdx.x, lane = tid & 63, wave = tid >> 6;   // 8 waves
  const u16* Te = (const u16*)(ws+OFF_TE);
  const float* Td = (const float*)(ws+OFF_TD);
  const float* mb = (const float*)(ws+OFF_M);
  __shared__ float ldsE[2][2][32];     // [dir][chunkIdx][u]
  int h0 = lane*8;
  float tdf[8], tdb[8], va[8];
  #pragma unroll
  for (int j = 0; j < 8; j++){
    tdf[j] = Td[b*H_ + h0 + j];
    tdb[j] = Td[(32+b)*H_ + h0 + j];
    va[j]  = v[h0 + j];
  }
  float mF = mb[b], mB = mb[32+b];
  for (int r = wave; r < 64; r += 8){
    int ci = r >> 5, u = r & 31;
    int s = (ci ? s0B : s0A) + u;
    const uint4 tv = *(const uint4*)(Te + ((size_t)(b*S_ + s))*H_ + h0);
    u32 wv[4] = {tv.x, tv.y, tv.z, tv.w};
    float af = 0.f, ab = 0.f;
    #pragma unroll
    for (int q = 0; q < 4; q++){
      int j = 2*q;
      float te0 = asf(wv[q] << 16);
      float te1 = asf(wv[q] & 0xffff0000u);
      float d0f = fmaf(te0, tdf[j],   1.0f);
      float d0b = fmaf(te0, tdb[j],   1.0f);
      af = fmaf((te0+tdf[j])*frcp(d0f), va[j], af);
      ab = fmaf((te0+tdb[j])*frcp(d0b), va[j], ab);
      float d1f = fmaf(te1, tdf[j+1], 1.0f);
      float d1b = fmaf(te1, tdb[j+1], 1.0f);
      af = fmaf((te1+tdf[j+1])*frcp(d1f), va[j+1], af);
      ab = fmaf((te1+tdb[j+1])*frcp(d1b), va[j+1], ab);
    }
    #pragma unroll
    for (int off = 1; off < 64; off <<= 1){
      af += __shfl_xor(af, off);
      ab += __shfl_xor(ab, off);
    }
    float ef = __expf(fminf(fmaxf(af - mF, -80.f), 80.f));
    float eb = __expf(fminf(fmaxf(ab - mB, -80.f), 80.f));
    if (lane == 0){ ldsE[0][ci][u] = ef; ldsE[1][ci][u] = eb; }
  }
  __syncthreads();
  if (tid < 2){
    float s = 0.f;
    for (int ci = 0; ci < 2; ci++)
      for (int u = 0; u < 32; u++) s += ldsE[tid][ci][u];
    atomicAdd((float*)(ws+OFF_SUME) + tid*32 + b, s);
  }
  if (tid < 192){
    int i0 = tid*4;
    const u16* E = (const u16*)(ws+OFF_EMB);
    float cf[4] = {0.f,0.f,0.f,0.f}, cb[4] = {0.f,0.f,0.f,0.f};
    for (int hf = 0; hf < 2; hf++){
      int sbase = hf ? s0B : s0A;
      for (int u = 0; u < 32; u++){
        ushort4 x4 = *(const ushort4*)(E + ((size_t)(b*S_ + sbase + u))*I_ + i0);
        float wf = ldsE[0][hf][u];
        float wb = ldsE[1][1-hf][31-u];   // emb[s] pairs with e_b[S-1-s]
        float x0 = bf2f(x4.x), x1 = bf2f(x4.y), x2 = bf2f(x4.z), x3 = bf2f(x4.w);
        cf[0] = fmaf(wf, x0, cf[0]); cf[1] = fmaf(wf, x1, cf[1]);
        cf[2] = fmaf(wf, x2, cf[2]); cf[3] = fmaf(wf, x3, cf[3]);
        cb[0] = fmaf(wb, x0, cb[0]); cb[1] = fmaf(wb, x1, cb[1]);
        cb[2] = fmaf(wb, x2, cb[2]); cb[3] = fmaf(wb, x3, cb[3]);
      }
    }
    float* ctx = (float*)(ws+OFF_CTX);
    #pragma unroll
    for (int z = 0; z < 4; z++){
      atomicAdd(&ctx[(size_t)b*I_ + i0 + z], cf[z]);
      atomicAdd(&ctx[(size_t)(32+b)*I_ + i0 + z], cb[z]);
    }
  }
}

// ---------------- per-step K3: ctx@WihL^T, LSTM cell, out projection ----------------
__global__ __launch_bounds__(256) void k_upd(char* ws,
        const float* bih_f, const float* bhh_f,
        const float* bih_b, const float* bhh_b,
        const float* Wout, const float* bout,
        float* out, int t){
  int wg = blockIdx.x;            // 64 = 2 dirs * 32 h-chunks
  int dir = wg >> 5, hc = wg & 31;
  int tid = threadIdx.x, lane = tid & 63, gt = tid >> 6;   // wave = gate (i,f,g,o)
  __shared__ u16 Abuf[32][776];   // normalized ctx, bf16, padded rows
  __shared__ float Gs[4][32][16];
  __shared__ float Hb[32][16];
  __shared__ float ldsInv[32];
  const float* ctx = (const float*)(ws+OFF_CTX) + (size_t)dir*32*I_;
  const float* se  = (const float*)(ws+OFF_SUME) + dir*32;
  if (tid < 32) ldsInv[tid] = 1.0f / fmaxf(se[tid], 1e-30f);
  __syncthreads();
  for (int idx = tid; idx < 32*I_; idx += 256){
    int bb = idx / I_, k = idx - bb*I_;
    Abuf[bb][k] = f2bf(ctx[(size_t)bb*I_ + k] * ldsInv[bb]);
  }
  __syncthreads();
  int lr = lane & 15, lkb = (lane>>4)*8, row4 = (lane>>4)*4;
  const u16* W = (const u16*)(ws+OFF_WIL) + (size_t)dir*G4H*I_;
  int n_g = gt*512 + hc*16 + lr;
  const u16* bp = W + (size_t)n_g*I_ + lkb;
  f32x4 acc0 = {0.f,0.f,0.f,0.f}, acc1 = {0.f,0.f,0.f,0.f};
  for (int k = 0; k < I_; k += 32){
    bf16x8 av0 = *(const bf16x8*)(&Abuf[lr][k + lkb]);
    bf16x8 av1 = *(const bf16x8*)(&Abuf[16 + lr][k + lkb]);
    bf16x8 bv  = *(const bf16x8*)(bp + k);
    acc0 = __builtin_amdgcn_mfma_f32_16x16x32_bf16(av0, bv, acc0, 0, 0, 0);
    acc1 = __builtin_amdgcn_mfma_f32_16x16x32_bf16(av1, bv, acc1, 0, 0, 0);
  }
  const float* xW = (const float*)(ws+OFF_XW);
  const float* hW = (const float*)(ws+OFF_HWH);
  const float* bih = dir ? bih_b : bih_f;
  const float* bhh = dir ? bhh_b : bhh_f;
  #pragma unroll
  for (int q = 0; q < 4; q++){
    int bb = row4 + q; int rr = dir*32 + bb;
    Gs[gt][bb][lr] = acc0[q] + xW[(size_t)rr*G4H + n_g] + hW[(size_t)rr*G4H + n_g]
                   + bih[n_g] + bhh[n_g];
  }
  #pragma unroll
  for (int q = 0; q < 4; q++){
    int bb = 16 + row4 + q; int rr = dir*32 + bb;
    Gs[gt][bb][lr] = acc1[q] + xW[(size_t)rr*G4H + n_g] + hW[(size_t)rr*G4H + n_g]
                   + bih[n_g] + bhh[n_g];
  }
  __syncthreads();
  float* cS = (float*)(ws+OFF_C);
  u16* hB = (u16*)(ws+OFF_H);
  for (int ci = tid; ci < 512; ci += 256){
    int bb = ci >> 4, j = ci & 15;
    int hg = hc*16 + j, rr = dir*32 + bb;
    float ig = sigm(Gs[0][bb][j]);
    float fg = sigm(Gs[1][bb][j]);
    float gg = tanhf(Gs[2][bb][j]);
    float og = sigm(Gs[3][bb][j]);
    float cn = fmaf(fg, cS[(size_t)rr*H_ + hg], ig*gg);
    float hn = og * tanhf(cn);
    cS[(size_t)rr*H_ + hg] = cn;
    hB[(size_t)rr*H_ + hg] = f2bf(hn);
    Hb[bb][j] = hn;
  }
  __syncthreads();
  // 320 work items (32 batches x 10 classes) on 256 threads -> loop (bugfix:
  // was `if (tid < 320)` which silently dropped batches 26..31)
  for (int idx = tid; idx < 320; idx += 256){
    int bb = idx / 10, cc = idx - bb*10;
    const float* wr = Wout + (size_t)cc*1024 + dir*512 + hc*16;
    float s = 0.f;
    #pragma unroll
    for (int j = 0; j < 16; j++) s = fmaf(Hb[bb][j], wr[j], s);
    if (dir == 0 && hc == 0) s += bout[cc];
    int st = dir ? (S_-1-t) : t;
    atomicAdd(&out[((size_t)bb*S_ + st)*C_ + cc], s);
  }
  if (hc == 0 && tid < 32){
    float* mbp = (float*)(ws+OFF_M);
    mbp[dir*32 + tid] += logf(fmaxf(se[tid], 1e-30f));
  }
}

// ---------------- host launcher ----------------
extern "C" void kernel_launch(void* const* d_in, const int* in_sizes, int n_in,
                              void* d_out, int out_size, void* d_ws, size_t ws_size,
                              hipStream_t stream){
  const float* emb   = (const float*)d_in[0];
  const float* Wenc  = (const float*)d_in[1];
  const float* benc  = (const float*)d_in[2];
  const float* Wdec  = (const float*)d_in[3];
  const float* bdec  = (const float*)d_in[4];
  const float* v     = (const float*)d_in[5];
  const float* Wih_f = (const float*)d_in[6];
  const float* Whh_f = (const float*)d_in[7];
  const float* bih_f = (const float*)d_in[8];
  const float* bhh_f = (const float*)d_in[9];
  const float* Wih_b = (const float*)d_in[10];
  const float* Whh_b = (const float*)d_in[11];
  const float* bih_b = (const float*)d_in[12];
  const float* bhh_b = (const float*)d_in[13];
  const float* Wout  = (const float*)d_in[14];
  const float* bout  = (const float*)d_in[15];
  float* out = (float*)d_out;
  char* ws = (char*)d_ws;
  if (ws_size < WS_NEED) return;   // fail loudly via validation

  k_setup<<<dim3(512), dim3(256), 0, stream>>>(ws, Wenc, Wdec, Whh_f, Whh_b, Wih_f, Wih_b, out);
  k_embconv<<<dim3(2048), dim3(256), 0, stream>>>(ws, emb);
  k_enc<<<dim3(8192), dim3(256), 0, stream>>>(ws, benc);
  for (int t = 0; t < S_; t++){
    k_step1<<<dim3(290), dim3(256), 0, stream>>>(ws, bdec, t);
    k_attn<<<dim3(256), dim3(512), 0, stream>>>(ws, v);
    k_upd<<<dim3(64), dim3(256), 0, stream>>>(ws, bih_f, bhh_f, bih_b, bhh_b, Wout, bout, out, t);
  }
}